// Round 10
// baseline (348.128 us; speedup 1.0000x reference)
//
#include <hip/hip_runtime.h>
#include <math.h>

#define B_ 128
#define D_ 128
#define P_ 4
#define M_ 100000
#define K_ 10
#define SCALE_ 10.0f
#define NEG_BLOCKS 512          // 128 blocks per p; 2 wave-pairs per block; 256 pairs per p
#define MMD_BLOCKS 128
#define POS_BLOCKS 128          // 512 (p,b) pairs / 4 waves
#define D2_CUT 120.0f           // d2 >= 120 -> exp(-10*sqrt(d2)) == 0.0f exactly (2^-158)

typedef short bf16x8 __attribute__((ext_vector_type(8)));
typedef float floatx4 __attribute__((ext_vector_type(4)));

// pack two fp32 -> two bf16 (truncate) in one v_perm_b32
__device__ inline unsigned pack_bf16_trunc(unsigned f0, unsigned f1) {
    return __builtin_amdgcn_perm(f1, f0, 0x07060302u);
}

// ---------- cross-lane helpers ----------
template <int CTRL>
__device__ inline float dpp_add(float v) {
    int x = __builtin_amdgcn_update_dpp(0, __builtin_bit_cast(int, v), CTRL, 0xF, 0xF, true);
    return v + __builtin_bit_cast(float, x);
}
__device__ inline float row16Sum(float v) {          // sum over lanes sharing l>>4
    v = dpp_add<0xB1>(v);
    v = dpp_add<0x4E>(v);
    v = dpp_add<0x141>(v);
    v = dpp_add<0x140>(v);
    return v;
}
__device__ inline float waveSum64(float v) {
    v = row16Sum(v);
    v += __shfl_xor(v, 16, 64);
    v += __shfl_xor(v, 32, 64);
    return v;
}
// legacy shfl butterfly (kept for mmd path: preserves summation order)
__device__ inline float waveReduceSumOld(float v) {
    #pragma unroll
    for (int off = 32; off > 0; off >>= 1) v += __shfl_xor(v, off, 64);
    return v;
}
__device__ inline float blockReduce128(float v, float* sh2) {  // 128-thread blocks
    v = waveSum64(v);
    int wid = threadIdx.x >> 6;
    if ((threadIdx.x & 63) == 0) sh2[wid] = v;
    __syncthreads();
    float r = sh2[0] + sh2[1];
    __syncthreads();
    return r;
}

// ---------- kernel A: normalize (transposed out) + f2 + zero s_neg + A-pack ----------
__global__ __launch_bounds__(128) void k_prep(const float* __restrict__ img,
                                              const float* __restrict__ txt,
                                              const float* __restrict__ local,
                                              float* imgT, float* txtT,
                                              float* a2i, float* a2t,
                                              float* f2w, float* s_neg,
                                              bf16x8* __restrict__ Apk) {
    __shared__ float sh2[2];
    int bid = blockIdx.x, t = threadIdx.x;
    if (bid < 256) {
        int row = bid & 127, which = bid >> 7;
        if (bid < 4) s_neg[bid * 128 + t] = 0.f;
        const float* src = which ? txt : img;
        float* dstT = which ? txtT : imgT;
        float* a2 = which ? a2t : a2i;
        float v = src[row * D_ + t];
        float s = blockReduce128(v * v, sh2);
        float n = v / sqrtf(s);
        dstT[t * 128 + row] = n;                  // transposed for coalesced mmd stream
        float s2 = blockReduce128(n * n, sh2);
        if (t == 0) a2[row] = s2;
    } else if (bid < 768) {
        int r = bid - 256;                        // 0..511 = (p,b)
        float v = local[(size_t)r * D_ + t];
        float s = blockReduce128(v * v, sh2);
        if (t == 0) f2w[r] = s;
    } else {
        // pack A = local[p] into bf16 MFMA fragments ONCE
        int g = (bid - 768) * 128 + t;            // 0..8191 global fragment id
        int p = g >> 11, f = g & 2047;
        int fl = f & 63, bt = (f >> 6) & 7, kc = f >> 9;
        int row = bt * 16 + (fl & 15);
        int col = kc * 32 + ((fl >> 4) & 3) * 8;
        const float* lp = local + (size_t)p * B_ * D_ + row * D_ + col;
        const uint4 u0 = *(const uint4*)lp;
        const uint4 u1 = *(const uint4*)(lp + 4);
        union { bf16x8 v; unsigned u[4]; } fr;
        fr.u[0] = pack_bf16_trunc(u0.x, u0.y);
        fr.u[1] = pack_bf16_trunc(u0.z, u0.w);
        fr.u[2] = pack_bf16_trunc(u1.x, u1.y);
        fr.u[3] = pack_bf16_trunc(u1.z, u1.w);
        Apk[g] = fr.v;                            // coalesced 16B store, fragment-linear
    }
}

// ---------- kernel B1: neg — VGPR-staged loads + ds_write, PINNED register budget ----
// R9 post-mortem: identical kernel ran with VGPR_Count=84 + 195MB scratch writes —
// the AMDGPU allocator chased 6 waves/EU occupancy (launch_bounds 2nd arg is only
// a FLOOR) and spilled ~15 regs/iter. Yet even hauling 3x payload it streamed
// 2.56 TB/s aggregate — 2.3x the global_load_lds path. Fix: pin waves/EU to
// (2,2) so the allocator gets the full 256-VGPR budget (plan ~185) and no
// incentive to spill. Everything else byte-identical to R9 for clean A/B.
__global__ __launch_bounds__(256)
__attribute__((amdgpu_waves_per_eu(2, 2)))
void k_neg(const float* __restrict__ centers,
           const int* __restrict__ ci,
           const int* __restrict__ posi,
           const float* __restrict__ f2w,
           const bf16x8* __restrict__ Apk,
           float* __restrict__ s_neg) {
    __shared__ float Bt[2][2][2048];   // [pair][buf][8KB] = 32 KB total
    const int t = threadIdx.x;
    const int w = t >> 6;
    const int l = t & 63;
    const int bid = blockIdx.x;
    const int p = bid >> 7;                       // 128 blocks per p
    const int g = bid & 127;
    const int pp = w >> 1;                        // pair within block (0,1)
    const int hm = w & 1;                         // member within pair (0,1)
    const int pairid = 2 * g + pp;                // 0..255 within p
    const int nt = (g < 53) ? 25 : 24;            // 6250 = 106*25 + 150*24 (exact)
    const int n16 = l & 15;
    const int q = l >> 4;

    // ---- A fragments (my bt-half) + f2 quad into registers (once) ----
    const bf16x8* Ap = Apk + (p << 11);
    bf16x8 af[4][4];                              // [kc][bt4] = 64 VGPR
    #pragma unroll
    for (int kc = 0; kc < 4; kc++)
        #pragma unroll
        for (int b4 = 0; b4 < 4; b4++)
            af[kc][b4] = Ap[kc * 512 + (hm * 4 + b4) * 64 + l];
    floatx4 f2r[4];
    #pragma unroll
    for (int b4 = 0; b4 < 4; b4++)
        f2r[b4] = *(const floatx4*)&f2w[p * 128 + (hm * 4 + b4) * 16 + q * 4];

    // ---- per-lane source offsets: contiguous 1KB/instr, bit-4 pre-swizzle ----
    // LDS image L[x] = T[x ^ (((x>>9)&7)<<4)]  (involution; T = row-major tile)
    unsigned srcoff[4];
    #pragma unroll
    for (int j = 0; j < 4; j++) {
        unsigned x = (unsigned)(hm * 4096 + j * 1024 + l * 16);
        unsigned s = (x >> 9) & 7u;
        srcoff[j] = x ^ (s << 4);                 // flips bit 4 only: coalescing intact
    }

    const char* tb0 = (const char*)(centers + (size_t)p * M_ * D_);
    char* myBt = (char*)&Bt[pp][0][0];
    char* wdst = myBt + hm * 4096 + l * 16;       // linear LDS dest base (this lane)

    // named 2-deep register slots; tile j lives in slot (j&1)
    uint4 sA[4], sB[4];
    auto LOADT_A = [&](int tl) {
        const char* src = tb0 + (size_t)tl * 8192;
        #pragma unroll
        for (int j = 0; j < 4; j++) sA[j] = *(const uint4*)(src + srcoff[j]);
    };
    auto LOADT_B = [&](int tl) {
        const char* src = tb0 + (size_t)tl * 8192;
        #pragma unroll
        for (int j = 0; j < 4; j++) sB[j] = *(const uint4*)(src + srcoff[j]);
    };
    auto DSW_A = [&](int buf) {
        char* dst = wdst + buf * 8192;
        #pragma unroll
        for (int j = 0; j < 4; j++) *(uint4*)(dst + j * 1024) = sA[j];
    };
    auto DSW_B = [&](int buf) {
        char* dst = wdst + buf * 8192;
        #pragma unroll
        for (int j = 0; j < 4; j++) *(uint4*)(dst + j * 1024) = sB[j];
    };

    float sacc[4][4];
    #pragma unroll
    for (int b4 = 0; b4 < 4; b4++)
        #pragma unroll
        for (int r = 0; r < 4; r++) sacc[b4][r] = 0.f;

    // ---- prologue: load tiles 0,1 to regs; write tile 0 to LDS (tile 1 stays in flight)
    LOADT_A(pairid);
    LOADT_B(pairid + 256);
    DSW_A(0);                                     // compiler waits vmcnt for sA only
    asm volatile("s_waitcnt lgkmcnt(0)" ::: "memory");
    __builtin_amdgcn_s_barrier();                 // raw barrier: sB loads survive

    int tli = pairid;
    const unsigned sw = (unsigned)((n16 & 7) << 4);
    for (int i = 0; i < nt; i++) {
        // ---- compute tile i from buf (i&1) (swizzled ds_read_b128, conflict-free) ----
        const char* bb = myBt + (i & 1) * 8192;
        float c2 = 0.f;
        bf16x8 bfr[4];
        #pragma unroll
        for (int kc = 0; kc < 4; kc++) {
            unsigned t0a = (unsigned)(n16 * 512 + kc * 128 + q * 32);
            union { floatx4 f; uint4 u; } h0, h1;
            h0.f = *(const floatx4*)(bb + (t0a ^ sw));
            h1.f = *(const floatx4*)(bb + ((t0a + 16) ^ sw));
            c2 += h0.f[0]*h0.f[0] + h0.f[1]*h0.f[1] + h0.f[2]*h0.f[2] + h0.f[3]*h0.f[3]
                + h1.f[0]*h1.f[0] + h1.f[1]*h1.f[1] + h1.f[2]*h1.f[2] + h1.f[3]*h1.f[3];
            union { bf16x8 v; unsigned uu[4]; } fr;
            fr.uu[0] = pack_bf16_trunc(h0.u.x, h0.u.y);
            fr.uu[1] = pack_bf16_trunc(h0.u.z, h0.u.w);
            fr.uu[2] = pack_bf16_trunc(h1.u.x, h1.u.y);
            fr.uu[3] = pack_bf16_trunc(h1.u.z, h1.u.w);
            bfr[kc] = fr.v;
        }
        c2 += __shfl_xor(c2, 16, 64);
        c2 += __shfl_xor(c2, 32, 64);
        const float c2v = c2;

        floatx4 acc[4];
        #pragma unroll
        for (int b4 = 0; b4 < 4; b4++) acc[b4] = (floatx4)(0.f);
        #pragma unroll
        for (int kc = 0; kc < 4; kc++) {
            #pragma unroll
            for (int b4 = 0; b4 < 4; b4++)
                acc[b4] = __builtin_amdgcn_mfma_f32_16x16x32_bf16(af[kc][b4], bfr[kc], acc[b4], 0, 0, 0);
        }

        // ---- epilogue: underflow-vote fast path ----
        float dmin = 1e30f;
        #pragma unroll
        for (int b4 = 0; b4 < 4; b4++) {
            #pragma unroll
            for (int r = 0; r < 4; r++) {
                float d2 = fmaf(-2.f, acc[b4][r], f2r[b4][r] + c2v);
                dmin = fminf(dmin, d2);
            }
        }
        if (__any(dmin < D2_CUT)) {
            // faithful slow path (cold): mask via direct scan
            const int gm = tli * 16 + n16;        // always < M_ (exact partition)
            float vm = 1.f;
            for (int ii = 0; ii < B_ * K_; ii++) {
                if (ci[ii] == gm) vm = 0.f;
            }
            for (int ii = 0; ii < B_; ii++) {
                if (posi[ii] == gm) vm = 0.f;
            }
            #pragma unroll
            for (int b4 = 0; b4 < 4; b4++) {
                #pragma unroll
                for (int r = 0; r < 4; r++) {
                    float d2 = fmaxf(fmaf(-2.f, acc[b4][r], f2r[b4][r] + c2v), 0.f);
                    if (d2 < D2_CUT) sacc[b4][r] += vm * expf(-SCALE_ * sqrtf(d2));
                }
            }
        }

        // ---- stage ahead: issue loads of tile i+2 (slot i&1, freed: tile i is in LDS);
        //      then write tile i+1's regs to buf (i+1)&1 (compiler waits only its vmcnt)
        if (i + 2 < nt) {
            if (i & 1) LOADT_B(tli + 512);
            else       LOADT_A(tli + 512);
        }
        if (i + 1 < nt) {
            if (i & 1) DSW_A((i + 1) & 1);
            else       DSW_B((i + 1) & 1);
        }
        asm volatile("s_waitcnt lgkmcnt(0)" ::: "memory");
        __builtin_amdgcn_s_barrier();             // pair's halves visible; loads in flight

        tli += 256;
    }

    // ---- per-wave reduce over m (lanes n16); guarded atomics (fast path: none) ----
    #pragma unroll
    for (int b4 = 0; b4 < 4; b4++) {
        #pragma unroll
        for (int r = 0; r < 4; r++) {
            float s = row16Sum(sacc[b4][r]);
            if (n16 == 0 && s != 0.f)
                atomicAdd(&s_neg[p * 128 + (hm * 4 + b4) * 16 + q * 4 + r], s);
        }
    }
}

// ---------- kernel B2: mmd + pos ----------
__global__ __launch_bounds__(256) void k_mp(const float* __restrict__ local,
                                            const float* __restrict__ centers,
                                            const float* __restrict__ imgT,
                                            const float* __restrict__ txtT,
                                            const float* __restrict__ a2i,
                                            const float* __restrict__ a2t,
                                            const int* __restrict__ ci,
                                            const int* __restrict__ mvid,
                                            const float* __restrict__ f2w,
                                            float* __restrict__ s_pos,
                                            double* __restrict__ mmd_part,
                                            float* __restrict__ out) {
    __shared__ float ri[128], rt[128], sh2[2];
    const int bid = blockIdx.x;
    const int t = threadIdx.x;
    const int w = t >> 6;
    const int l = t & 63;

    if (bid < MMD_BLOCKS) {
        // ================= mmd (row i); threads 0-127 active, coalesced stream =======
        const int i = bid;
        if (t < 128) {
            ri[t] = imgT[t * 128 + i];            // row i gather (once)
            rt[t] = txtT[t * 128 + i];
        }
        __syncthreads();
        float kxx = 0.f, kyy = 0.f, kxy = 0.f;
        if (t < 128) {
            float dxx = 0.f, dyy = 0.f, dxy = 0.f;
            #pragma unroll 4
            for (int d = 0; d < D_; d++) {
                float rid = ri[d], rtd = rt[d];
                float av = imgT[d * 128 + t];     // coalesced
                float bv = txtT[d * 128 + t];
                dxx = fmaf(rid, av, dxx);
                dyy = fmaf(rtd, bv, dyy);
                dxy = fmaf(rid, bv, dxy);
            }
            kxx = (i == t) ? 0.f : expf(-fmaxf(a2i[i] + a2i[t] - 2.f * dxx, 0.f) * 0.5f);
            kyy = (i == t) ? 0.f : expf(-fmaxf(a2t[i] + a2t[t] - 2.f * dyy, 0.f) * 0.5f);
            kxy = expf(-fmaxf(a2i[i] + a2t[t] - 2.f * dxy, 0.f) * 0.5f);
        }
        float sxx = waveReduceSumOld(kxx);
        float syy = waveReduceSumOld(kyy);
        float sxy = waveReduceSumOld(kxy);
        __syncthreads();
        if (t == 0)  { sh2[0] = sxx; }
        if (t == 64) { sh2[1] = sxx; }
        __syncthreads();
        float txx = sh2[0] + sh2[1];
        __syncthreads();
        if (t == 0)  { sh2[0] = syy; }
        if (t == 64) { sh2[1] = syy; }
        __syncthreads();
        float tyy = sh2[0] + sh2[1];
        __syncthreads();
        if (t == 0)  { sh2[0] = sxy; }
        if (t == 64) { sh2[1] = sxy; }
        __syncthreads();
        float txy = sh2[0] + sh2[1];
        if (t == 0) {
            mmd_part[i] = (double)txx;
            mmd_part[128 + i] = (double)tyy;
            mmd_part[256 + i] = (double)txy;
        }
    } else {
        // ================= pos: one wave per (p,b), 4 per block ======================
        const int pair = (bid - MMD_BLOCKS) * 4 + w;   // 0..511
        const int p = pair >> 7, b = pair & 127;
        const float* f = local + (size_t)pair * D_;
        float f0 = f[l], f1 = f[l + 64];
        float f2v = f2w[pair];
        const float* cb = centers + (size_t)p * M_ * D_;
        float s = 0.f;
        #pragma unroll
        for (int k = 0; k < K_; k++) {
            int idx = ci[b * K_ + k];
            const float* c = cb + (size_t)idx * D_;
            float c0 = c[l], c1 = c[l + 64];
            float p2 = waveSum64(c0 * c0 + c1 * c1);
            float fp = waveSum64(f0 * c0 + f1 * c1);
            float d2 = fmaxf(f2v + p2 - 2.f * fp, 0.f);
            if (d2 < D2_CUT) s += expf(-SCALE_ * sqrtf(d2));   // wave-uniform branch
        }
        if (l == 0) s_pos[pair] = s;
        if (p == 0 && l < K_) {
            int ix = ci[b * K_ + l];
            out[3 + b * K_ + l] = (float)mvid[ix];
        }
    }
}

// ---------- kernel C: final scalars ----------
__global__ __launch_bounds__(512) void k_final(const float* __restrict__ s_pos,
                                               const float* __restrict__ s_neg,
                                               const double* __restrict__ mmd_part,
                                               float* out) {
    __shared__ float red[512];
    __shared__ float lp_[4];
    int t = threadIdx.x;
    float x = logf(s_pos[t]);
    float y = logf(s_neg[t]);
    red[t] = -x + y;
    __syncthreads();
    for (int s = 64; s > 0; s >>= 1) {
        if ((t & 127) < s) red[t] += red[t + s];
        __syncthreads();
    }
    if ((t & 127) == 0) {
        float lv = red[t] / (float)B_;
        if (isnan(lv)) lv = 0.f;
        lp_[t >> 7] = lv;
    }
    __syncthreads();
    if (t == 0) {
        float local_loss = (lp_[0] + lp_[1] + lp_[2] + lp_[3]) / (float)P_;
        double sxx = 0.0, syy = 0.0, sxy = 0.0;
        for (int i = 0; i < 128; i++) {
            sxx += mmd_part[i];
            syy += mmd_part[128 + i];
            sxy += mmd_part[256 + i];
        }
        double denom = 128.0 * 127.0;
        float mmd = (float)(sxx / denom + syy / denom - 2.0 * (sxy / (128.0 * 128.0)));
        out[0] = local_loss + mmd;
        out[1] = local_loss;
        out[2] = mmd;
    }
}

extern "C" void kernel_launch(void* const* d_in, const int* in_sizes, int n_in,
                              void* d_out, int out_size, void* d_ws, size_t ws_size,
                              hipStream_t stream) {
    const float* img     = (const float*)d_in[0];
    const float* txt     = (const float*)d_in[1];
    const float* local   = (const float*)d_in[2];
    const float* centers = (const float*)d_in[3];
    const int*   ci      = (const int*)d_in[4];
    const int*   posi    = (const int*)d_in[5];
    const int*   mvid    = (const int*)d_in[6];
    float* out = (float*)d_out;

    char* ws = (char*)d_ws;
    float*  imgT     = (float*)(ws + 0);
    float*  txtT     = (float*)(ws + 65536);
    float*  a2i      = (float*)(ws + 131072);
    float*  a2t      = (float*)(ws + 131584);
    float*  f2w      = (float*)(ws + 132096);
    float*  s_pos    = (float*)(ws + 134144);
    float*  s_neg    = (float*)(ws + 136192);
    double* mmd_part = (double*)(ws + 138240);
    bf16x8* Apk      = (bf16x8*)(ws + 147456);   // 128 KB, 16B-aligned

    k_prep<<<832, 128, 0, stream>>>(img, txt, local, imgT, txtT, a2i, a2t, f2w, s_neg, Apk);
    k_neg<<<NEG_BLOCKS, 256, 0, stream>>>(centers, ci, posi, f2w, Apk, s_neg);
    k_mp<<<MMD_BLOCKS + POS_BLOCKS, 256, 0, stream>>>(
        local, centers, imgT, txtT, a2i, a2t, ci, mvid, f2w, s_pos, mmd_part, out);
    k_final<<<1, 512, 0, stream>>>(s_pos, s_neg, mmd_part, out);
}

// Round 11
// 318.580 us; speedup vs baseline: 1.0927x; 1.0927x over previous
//
#include <hip/hip_runtime.h>
#include <math.h>

#define B_ 128
#define D_ 128
#define P_ 4
#define M_ 100000
#define K_ 10
#define SCALE_ 10.0f
#define NEG_BLOCKS 512          // 128 blocks per p; 2 wave-pairs per block; 256 pairs per p
#define MMD_BLOCKS 128
#define POS_BLOCKS 128          // 512 (p,b) pairs / 4 waves
#define D2_CUT 120.0f           // d2 >= 120 -> exp(-10*sqrt(d2)) == 0.0f exactly (2^-158)

typedef short bf16x8 __attribute__((ext_vector_type(8)));
typedef float floatx4 __attribute__((ext_vector_type(4)));

// pack two fp32 -> two bf16 (truncate) in one v_perm_b32
__device__ inline unsigned pack_bf16_trunc(unsigned f0, unsigned f1) {
    return __builtin_amdgcn_perm(f1, f0, 0x07060302u);
}

// ---------- cross-lane helpers ----------
template <int CTRL>
__device__ inline float dpp_add(float v) {
    int x = __builtin_amdgcn_update_dpp(0, __builtin_bit_cast(int, v), CTRL, 0xF, 0xF, true);
    return v + __builtin_bit_cast(float, x);
}
__device__ inline float row16Sum(float v) {          // sum over lanes sharing l>>4
    v = dpp_add<0xB1>(v);
    v = dpp_add<0x4E>(v);
    v = dpp_add<0x141>(v);
    v = dpp_add<0x140>(v);
    return v;
}
__device__ inline float waveSum64(float v) {
    v = row16Sum(v);
    v += __shfl_xor(v, 16, 64);
    v += __shfl_xor(v, 32, 64);
    return v;
}
// legacy shfl butterfly (kept for mmd path: preserves summation order)
__device__ inline float waveReduceSumOld(float v) {
    #pragma unroll
    for (int off = 32; off > 0; off >>= 1) v += __shfl_xor(v, off, 64);
    return v;
}
__device__ inline float blockReduce128(float v, float* sh2) {  // 128-thread blocks
    v = waveSum64(v);
    int wid = threadIdx.x >> 6;
    if ((threadIdx.x & 63) == 0) sh2[wid] = v;
    __syncthreads();
    float r = sh2[0] + sh2[1];
    __syncthreads();
    return r;
}

// ---------- kernel A: normalize (transposed out) + f2 + zero s_neg + A-pack ----------
__global__ __launch_bounds__(128) void k_prep(const float* __restrict__ img,
                                              const float* __restrict__ txt,
                                              const float* __restrict__ local,
                                              float* imgT, float* txtT,
                                              float* a2i, float* a2t,
                                              float* f2w, float* s_neg,
                                              bf16x8* __restrict__ Apk) {
    __shared__ float sh2[2];
    int bid = blockIdx.x, t = threadIdx.x;
    if (bid < 256) {
        int row = bid & 127, which = bid >> 7;
        if (bid < 4) s_neg[bid * 128 + t] = 0.f;
        const float* src = which ? txt : img;
        float* dstT = which ? txtT : imgT;
        float* a2 = which ? a2t : a2i;
        float v = src[row * D_ + t];
        float s = blockReduce128(v * v, sh2);
        float n = v / sqrtf(s);
        dstT[t * 128 + row] = n;                  // transposed for coalesced mmd stream
        float s2 = blockReduce128(n * n, sh2);
        if (t == 0) a2[row] = s2;
    } else if (bid < 768) {
        int r = bid - 256;                        // 0..511 = (p,b)
        float v = local[(size_t)r * D_ + t];
        float s = blockReduce128(v * v, sh2);
        if (t == 0) f2w[r] = s;
    } else {
        // pack A = local[p] into bf16 MFMA fragments ONCE
        int g = (bid - 768) * 128 + t;            // 0..8191 global fragment id
        int p = g >> 11, f = g & 2047;
        int fl = f & 63, bt = (f >> 6) & 7, kc = f >> 9;
        int row = bt * 16 + (fl & 15);
        int col = kc * 32 + ((fl >> 4) & 3) * 8;
        const float* lp = local + (size_t)p * B_ * D_ + row * D_ + col;
        const uint4 u0 = *(const uint4*)lp;
        const uint4 u1 = *(const uint4*)(lp + 4);
        union { bf16x8 v; unsigned u[4]; } fr;
        fr.u[0] = pack_bf16_trunc(u0.x, u0.y);
        fr.u[1] = pack_bf16_trunc(u0.z, u0.w);
        fr.u[2] = pack_bf16_trunc(u1.x, u1.y);
        fr.u[3] = pack_bf16_trunc(u1.z, u1.w);
        Apk[g] = fr.v;                            // coalesced 16B store, fragment-linear
    }
}

// ---------- kernel B: neg (R5 best-known structure, contiguous ranges) + mmd + pos ---
// Consolidation on the measured best (R5=324.2us; spill-free DMA transport).
// Changes vs R5: (1) mmd+pos merged into this launch (union keeps LDS at 48KB ->
// 3 blocks/CU preserved; hides k_mp's ~12us + one launch gap); (2) each pair
// owns a CONTIGUOUS tile range [base, base+nt) — a sequential ~200KB stream per
// pair (copy-benchmark-like) instead of 2MB-strided 8KB hops (stream locality).
// R9/R10 lesson: reg-staged arrays + asm barriers => scratch traffic on this
// toolchain; global_load_lds transport never spilled. Staying on DMA.
__global__ __launch_bounds__(256, 2) void k_negmp(const float* __restrict__ centers,
                                                  const float* __restrict__ local,
                                                  const float* __restrict__ imgT,
                                                  const float* __restrict__ txtT,
                                                  const float* __restrict__ a2i,
                                                  const float* __restrict__ a2t,
                                                  const int* __restrict__ ci,
                                                  const int* __restrict__ posi,
                                                  const int* __restrict__ mvid,
                                                  const float* __restrict__ f2w,
                                                  const bf16x8* __restrict__ Apk,
                                                  float* __restrict__ s_neg,
                                                  float* __restrict__ s_pos,
                                                  double* __restrict__ mmd_part,
                                                  float* __restrict__ out) {
    union Smem {
        struct { float Bt[2][3][2048]; } n;       // [pair][buf][8KB] = 48 KB
        struct { float ri[128], rt[128], sh2[2]; } m;
    };
    __shared__ Smem sm;
    const int t = threadIdx.x;
    const int w = t >> 6;
    const int l = t & 63;
    const int bid = blockIdx.x;

    if (bid < NEG_BLOCKS) {
        // ================= neg =================
        const int p = bid >> 7;                   // 128 blocks per p
        const int g = bid & 127;
        const int pp = w >> 1;                    // pair within block (0,1)
        const int hm = w & 1;                     // member within pair (0,1)
        const int pairid = 2 * g + pp;            // 0..255 within p
        // contiguous partition: first 106 pairs 25 tiles, rest 24 (6250 exact);
        // g<53 <=> pairid<106, so nt is block-uniform (barrier schedule needs it)
        const int nt = (g < 53) ? 25 : 24;
        const int base = (pairid < 106) ? pairid * 25 : 2650 + (pairid - 106) * 24;
        const int n16 = l & 15;
        const int q = l >> 4;

        // ---- A fragments (my bt-half) + f2 quad into registers (once) ----
        const bf16x8* Ap = Apk + (p << 11);
        bf16x8 af[4][4];                          // [kc][bt4] = 64 VGPR
        #pragma unroll
        for (int kc = 0; kc < 4; kc++)
            #pragma unroll
            for (int b4 = 0; b4 < 4; b4++)
                af[kc][b4] = Ap[kc * 512 + (hm * 4 + b4) * 64 + l];
        floatx4 f2r[4];
        #pragma unroll
        for (int b4 = 0; b4 < 4; b4++)
            f2r[b4] = *(const floatx4*)&f2w[p * 128 + (hm * 4 + b4) * 16 + q * 4];

        // ---- per-lane DMA source offsets: contiguous 1KB/instr, bit-4 pre-swizzle ----
        // LDS image L[x] = T[x ^ (((x>>9)&7)<<4)]  (involution; T = row-major tile)
        unsigned srcoff[4];
        #pragma unroll
        for (int j = 0; j < 4; j++) {
            unsigned x = (unsigned)(hm * 4096 + j * 1024 + l * 16);
            unsigned s = (x >> 9) & 7u;
            srcoff[j] = x ^ (s << 4);             // flips bit 4 only: coalescing intact
        }

        const char* tb0 = (const char*)(centers + (size_t)p * M_ * D_);
        char* myBt = (char*)&sm.n.Bt[pp][0][0];

        auto DMA = [&](int tl, int buf) {         // half-tile (4KB) per wave, 4 instrs
            const char* src = tb0 + (size_t)tl * 8192;
            char* dst = myBt + buf * 8192 + hm * 4096;
            #pragma unroll
            for (int j = 0; j < 4; j++) {
                __builtin_amdgcn_global_load_lds(
                    (const __attribute__((address_space(1))) void*)(src + srcoff[j]),
                    (__attribute__((address_space(3))) void*)(dst + j * 1024),
                    16, 0, 0);
            }
        };

        float sacc[4][4];
        #pragma unroll
        for (int b4 = 0; b4 < 4; b4++)
            #pragma unroll
            for (int r = 0; r < 4; r++) sacc[b4][r] = 0.f;

        // ---- prologue: tiles base, base+1 in flight; drain tile 0 (keeps tile 1) ----
        DMA(base, 0);
        DMA(base + 1, 1);
        asm volatile("s_waitcnt vmcnt(4)" ::: "memory");
        __builtin_amdgcn_s_barrier();

        int ib = 0;
        const unsigned sw = (unsigned)((n16 & 7) << 4);
        for (int i = 0; i < nt; i++) {
            // ---- compute tile base+i from buf ib (swizzled ds_read_b128) ----
            const char* bb = myBt + ib * 8192;
            float c2 = 0.f;
            bf16x8 bfr[4];
            #pragma unroll
            for (int kc = 0; kc < 4; kc++) {
                unsigned t0a = (unsigned)(n16 * 512 + kc * 128 + q * 32);
                union { floatx4 f; uint4 u; } h0, h1;
                h0.f = *(const floatx4*)(bb + (t0a ^ sw));
                h1.f = *(const floatx4*)(bb + ((t0a + 16) ^ sw));
                c2 += h0.f[0]*h0.f[0] + h0.f[1]*h0.f[1] + h0.f[2]*h0.f[2] + h0.f[3]*h0.f[3]
                    + h1.f[0]*h1.f[0] + h1.f[1]*h1.f[1] + h1.f[2]*h1.f[2] + h1.f[3]*h1.f[3];
                union { bf16x8 v; unsigned uu[4]; } fr;
                fr.uu[0] = pack_bf16_trunc(h0.u.x, h0.u.y);
                fr.uu[1] = pack_bf16_trunc(h0.u.z, h0.u.w);
                fr.uu[2] = pack_bf16_trunc(h1.u.x, h1.u.y);
                fr.uu[3] = pack_bf16_trunc(h1.u.z, h1.u.w);
                bfr[kc] = fr.v;
            }
            c2 += __shfl_xor(c2, 16, 64);
            c2 += __shfl_xor(c2, 32, 64);
            const float c2v = c2;

            floatx4 acc[4];
            #pragma unroll
            for (int b4 = 0; b4 < 4; b4++) acc[b4] = (floatx4)(0.f);
            #pragma unroll
            for (int kc = 0; kc < 4; kc++) {
                #pragma unroll
                for (int b4 = 0; b4 < 4; b4++)
                    acc[b4] = __builtin_amdgcn_mfma_f32_16x16x32_bf16(af[kc][b4], bfr[kc], acc[b4], 0, 0, 0);
            }

            // ---- epilogue: underflow-vote fast path ----
            float dmin = 1e30f;
            #pragma unroll
            for (int b4 = 0; b4 < 4; b4++) {
                #pragma unroll
                for (int r = 0; r < 4; r++) {
                    float d2 = fmaf(-2.f, acc[b4][r], f2r[b4][r] + c2v);
                    dmin = fminf(dmin, d2);
                }
            }
            if (__any(dmin < D2_CUT)) {
                // faithful slow path (cold): mask via direct scan
                const int gm = (base + i) * 16 + n16;   // always < M_ (exact partition)
                float vm = 1.f;
                for (int ii = 0; ii < B_ * K_; ii++) {
                    if (ci[ii] == gm) vm = 0.f;
                }
                for (int ii = 0; ii < B_; ii++) {
                    if (posi[ii] == gm) vm = 0.f;
                }
                #pragma unroll
                for (int b4 = 0; b4 < 4; b4++) {
                    #pragma unroll
                    for (int r = 0; r < 4; r++) {
                        float d2 = fmaxf(fmaf(-2.f, acc[b4][r], f2r[b4][r] + c2v), 0.f);
                        if (d2 < D2_CUT) sacc[b4][r] += vm * expf(-SCALE_ * sqrtf(d2));
                    }
                }
            }

            // ---- issue tile base+i+2 into the buffer freed by compute(i-1) ----
            if (i + 2 < nt) {
                int b2 = ib + 2; if (b2 >= 3) b2 -= 3;
                DMA(base + i + 2, b2);
                asm volatile("s_waitcnt vmcnt(4)" ::: "memory");   // drain i+1, keep i+2
            } else if (i + 1 < nt) {
                asm volatile("s_waitcnt vmcnt(0)" ::: "memory");   // drain last tile
            }
            __builtin_amdgcn_s_barrier();         // partner drained too (nt block-uniform)

            ib = (ib + 1 == 3) ? 0 : ib + 1;
        }

        // ---- per-wave reduce over m (lanes n16); guarded atomics (fast path: none) ----
        #pragma unroll
        for (int b4 = 0; b4 < 4; b4++) {
            #pragma unroll
            for (int r = 0; r < 4; r++) {
                float s = row16Sum(sacc[b4][r]);
                if (n16 == 0 && s != 0.f)
                    atomicAdd(&s_neg[p * 128 + (hm * 4 + b4) * 16 + q * 4 + r], s);
            }
        }
    } else if (bid < NEG_BLOCKS + MMD_BLOCKS) {
        // ================= mmd (row i); threads 0-127 active, coalesced stream =======
        const int i = bid - NEG_BLOCKS;
        if (t < 128) {
            sm.m.ri[t] = imgT[t * 128 + i];       // row i gather (once)
            sm.m.rt[t] = txtT[t * 128 + i];
        }
        __syncthreads();
        float kxx = 0.f, kyy = 0.f, kxy = 0.f;
        if (t < 128) {
            float dxx = 0.f, dyy = 0.f, dxy = 0.f;
            #pragma unroll 4
            for (int d = 0; d < D_; d++) {
                float rid = sm.m.ri[d], rtd = sm.m.rt[d];
                float av = imgT[d * 128 + t];     // coalesced
                float bv = txtT[d * 128 + t];
                dxx = fmaf(rid, av, dxx);
                dyy = fmaf(rtd, bv, dyy);
                dxy = fmaf(rid, bv, dxy);
            }
            kxx = (i == t) ? 0.f : expf(-fmaxf(a2i[i] + a2i[t] - 2.f * dxx, 0.f) * 0.5f);
            kyy = (i == t) ? 0.f : expf(-fmaxf(a2t[i] + a2t[t] - 2.f * dyy, 0.f) * 0.5f);
            kxy = expf(-fmaxf(a2i[i] + a2t[t] - 2.f * dxy, 0.f) * 0.5f);
        }
        float sxx = waveReduceSumOld(kxx);
        float syy = waveReduceSumOld(kyy);
        float sxy = waveReduceSumOld(kxy);
        __syncthreads();
        if (t == 0)  { sm.m.sh2[0] = sxx; }
        if (t == 64) { sm.m.sh2[1] = sxx; }
        __syncthreads();
        float txx = sm.m.sh2[0] + sm.m.sh2[1];
        __syncthreads();
        if (t == 0)  { sm.m.sh2[0] = syy; }
        if (t == 64) { sm.m.sh2[1] = syy; }
        __syncthreads();
        float tyy = sm.m.sh2[0] + sm.m.sh2[1];
        __syncthreads();
        if (t == 0)  { sm.m.sh2[0] = sxy; }
        if (t == 64) { sm.m.sh2[1] = sxy; }
        __syncthreads();
        float txy = sm.m.sh2[0] + sm.m.sh2[1];
        if (t == 0) {
            mmd_part[i] = (double)txx;
            mmd_part[128 + i] = (double)tyy;
            mmd_part[256 + i] = (double)txy;
        }
    } else {
        // ================= pos: one wave per (p,b), 4 per block ======================
        const int pair = (bid - (NEG_BLOCKS + MMD_BLOCKS)) * 4 + w;   // 0..511
        const int p = pair >> 7, b = pair & 127;
        const float* f = local + (size_t)pair * D_;
        float f0 = f[l], f1 = f[l + 64];
        float f2v = f2w[pair];
        const float* cb = centers + (size_t)p * M_ * D_;
        float s = 0.f;
        #pragma unroll
        for (int k = 0; k < K_; k++) {
            int idx = ci[b * K_ + k];
            const float* c = cb + (size_t)idx * D_;
            float c0 = c[l], c1 = c[l + 64];
            float p2 = waveSum64(c0 * c0 + c1 * c1);
            float fp = waveSum64(f0 * c0 + f1 * c1);
            float d2 = fmaxf(f2v + p2 - 2.f * fp, 0.f);
            if (d2 < D2_CUT) s += expf(-SCALE_ * sqrtf(d2));   // wave-uniform branch
        }
        if (l == 0) s_pos[pair] = s;
        if (p == 0 && l < K_) {
            int ix = ci[b * K_ + l];
            out[3 + b * K_ + l] = (float)mvid[ix];
        }
    }
}

// ---------- kernel C: final scalars ----------
__global__ __launch_bounds__(512) void k_final(const float* __restrict__ s_pos,
                                               const float* __restrict__ s_neg,
                                               const double* __restrict__ mmd_part,
                                               float* out) {
    __shared__ float red[512];
    __shared__ float lp_[4];
    int t = threadIdx.x;
    float x = logf(s_pos[t]);
    float y = logf(s_neg[t]);
    red[t] = -x + y;
    __syncthreads();
    for (int s = 64; s > 0; s >>= 1) {
        if ((t & 127) < s) red[t] += red[t + s];
        __syncthreads();
    }
    if ((t & 127) == 0) {
        float lv = red[t] / (float)B_;
        if (isnan(lv)) lv = 0.f;
        lp_[t >> 7] = lv;
    }
    __syncthreads();
    if (t == 0) {
        float local_loss = (lp_[0] + lp_[1] + lp_[2] + lp_[3]) / (float)P_;
        double sxx = 0.0, syy = 0.0, sxy = 0.0;
        for (int i = 0; i < 128; i++) {
            sxx += mmd_part[i];
            syy += mmd_part[128 + i];
            sxy += mmd_part[256 + i];
        }
        double denom = 128.0 * 127.0;
        float mmd = (float)(sxx / denom + syy / denom - 2.0 * (sxy / (128.0 * 128.0)));
        out[0] = local_loss + mmd;
        out[1] = local_loss;
        out[2] = mmd;
    }
}

extern "C" void kernel_launch(void* const* d_in, const int* in_sizes, int n_in,
                              void* d_out, int out_size, void* d_ws, size_t ws_size,
                              hipStream_t stream) {
    const float* img     = (const float*)d_in[0];
    const float* txt     = (const float*)d_in[1];
    const float* local   = (const float*)d_in[2];
    const float* centers = (const float*)d_in[3];
    const int*   ci      = (const int*)d_in[4];
    const int*   posi    = (const int*)d_in[5];
    const int*   mvid    = (const int*)d_in[6];
    float* out = (float*)d_out;

    char* ws = (char*)d_ws;
    float*  imgT     = (float*)(ws + 0);
    float*  txtT     = (float*)(ws + 65536);
    float*  a2i      = (float*)(ws + 131072);
    float*  a2t      = (float*)(ws + 131584);
    float*  f2w      = (float*)(ws + 132096);
    float*  s_pos    = (float*)(ws + 134144);
    float*  s_neg    = (float*)(ws + 136192);
    double* mmd_part = (double*)(ws + 138240);
    bf16x8* Apk      = (bf16x8*)(ws + 147456);   // 128 KB, 16B-aligned

    k_prep<<<832, 128, 0, stream>>>(img, txt, local, imgT, txtT, a2i, a2t, f2w, s_neg, Apk);
    k_negmp<<<NEG_BLOCKS + MMD_BLOCKS + POS_BLOCKS, 256, 0, stream>>>(
        centers, local, imgT, txtT, a2i, a2t, ci, posi, mvid, f2w, Apk,
        s_neg, s_pos, mmd_part, out);
    k_final<<<1, 512, 0, stream>>>(s_pos, s_neg, mmd_part, out);
}

// Round 12
// 306.762 us; speedup vs baseline: 1.1348x; 1.0385x over previous
//
#include <hip/hip_runtime.h>
#include <math.h>

#define B_ 128
#define D_ 128
#define P_ 4
#define M_ 100000
#define K_ 10
#define SCALE_ 10.0f
#define NEG_BLOCKS 1024         // 256 blocks per p; 2 wave-pairs per block; 512 pairs per p
#define MMD_BLOCKS 128
#define POS_BLOCKS 128          // 512 (p,b) pairs / 4 waves
#define D2_CUT 120.0f           // d2 >= 120 -> exp(-10*sqrt(d2)) == 0.0f exactly (2^-158)

typedef short bf16x8 __attribute__((ext_vector_type(8)));
typedef float floatx4 __attribute__((ext_vector_type(4)));

// pack two fp32 -> two bf16 (truncate) in one v_perm_b32
__device__ inline unsigned pack_bf16_trunc(unsigned f0, unsigned f1) {
    return __builtin_amdgcn_perm(f1, f0, 0x07060302u);
}

// ---------- cross-lane helpers ----------
template <int CTRL>
__device__ inline float dpp_add(float v) {
    int x = __builtin_amdgcn_update_dpp(0, __builtin_bit_cast(int, v), CTRL, 0xF, 0xF, true);
    return v + __builtin_bit_cast(float, x);
}
__device__ inline float row16Sum(float v) {          // sum over lanes sharing l>>4
    v = dpp_add<0xB1>(v);
    v = dpp_add<0x4E>(v);
    v = dpp_add<0x141>(v);
    v = dpp_add<0x140>(v);
    return v;
}
__device__ inline float waveSum64(float v) {
    v = row16Sum(v);
    v += __shfl_xor(v, 16, 64);
    v += __shfl_xor(v, 32, 64);
    return v;
}
// legacy shfl butterfly (kept for mmd path: preserves summation order)
__device__ inline float waveReduceSumOld(float v) {
    #pragma unroll
    for (int off = 32; off > 0; off >>= 1) v += __shfl_xor(v, off, 64);
    return v;
}
__device__ inline float blockReduce128(float v, float* sh2) {  // 128-thread blocks
    v = waveSum64(v);
    int wid = threadIdx.x >> 6;
    if ((threadIdx.x & 63) == 0) sh2[wid] = v;
    __syncthreads();
    float r = sh2[0] + sh2[1];
    __syncthreads();
    return r;
}

// ---------- kernel A: normalize (transposed out) + f2 + zero s_neg + A-pack ----------
__global__ __launch_bounds__(128) void k_prep(const float* __restrict__ img,
                                              const float* __restrict__ txt,
                                              const float* __restrict__ local,
                                              float* imgT, float* txtT,
                                              float* a2i, float* a2t,
                                              float* f2w, float* s_neg,
                                              bf16x8* __restrict__ Apk) {
    __shared__ float sh2[2];
    int bid = blockIdx.x, t = threadIdx.x;
    if (bid < 256) {
        int row = bid & 127, which = bid >> 7;
        if (bid < 4) s_neg[bid * 128 + t] = 0.f;
        const float* src = which ? txt : img;
        float* dstT = which ? txtT : imgT;
        float* a2 = which ? a2t : a2i;
        float v = src[row * D_ + t];
        float s = blockReduce128(v * v, sh2);
        float n = v / sqrtf(s);
        dstT[t * 128 + row] = n;                  // transposed for coalesced mmd stream
        float s2 = blockReduce128(n * n, sh2);
        if (t == 0) a2[row] = s2;
    } else if (bid < 768) {
        int r = bid - 256;                        // 0..511 = (p,b)
        float v = local[(size_t)r * D_ + t];
        float s = blockReduce128(v * v, sh2);
        if (t == 0) f2w[r] = s;
    } else {
        // pack A = local[p] into bf16 MFMA fragments ONCE
        int g = (bid - 768) * 128 + t;            // 0..8191 global fragment id
        int p = g >> 11, f = g & 2047;
        int fl = f & 63, bt = (f >> 6) & 7, kc = f >> 9;
        int row = bt * 16 + (fl & 15);
        int col = kc * 32 + ((fl >> 4) & 3) * 8;
        const float* lp = local + (size_t)p * B_ * D_ + row * D_ + col;
        const uint4 u0 = *(const uint4*)lp;
        const uint4 u1 = *(const uint4*)(lp + 4);
        union { bf16x8 v; unsigned u[4]; } fr;
        fr.u[0] = pack_bf16_trunc(u0.x, u0.y);
        fr.u[1] = pack_bf16_trunc(u0.z, u0.w);
        fr.u[2] = pack_bf16_trunc(u1.x, u1.y);
        fr.u[3] = pack_bf16_trunc(u1.z, u1.w);
        Apk[g] = fr.v;                            // coalesced 16B store, fragment-linear
    }
}

// ---------- kernel B: neg (R11 structure, 2x blocks = 2x streams/CU) + mmd + pos -----
// R11 (512 blocks, merged, contiguous ranges) = best, 318.6us. Single change here:
// NEG_BLOCKS 512 -> 1024. LDS stays 48KB -> 3 blocks/CU resident (6 independent
// pair-streams per CU, +50%) + backfill as blocks drain. Isolates the one never-
// tested variable: independent streams per CU (concurrency), with the register
// budget and schedule untouched.
__global__ __launch_bounds__(256, 2) void k_negmp(const float* __restrict__ centers,
                                                  const float* __restrict__ local,
                                                  const float* __restrict__ imgT,
                                                  const float* __restrict__ txtT,
                                                  const float* __restrict__ a2i,
                                                  const float* __restrict__ a2t,
                                                  const int* __restrict__ ci,
                                                  const int* __restrict__ posi,
                                                  const int* __restrict__ mvid,
                                                  const float* __restrict__ f2w,
                                                  const bf16x8* __restrict__ Apk,
                                                  float* __restrict__ s_neg,
                                                  float* __restrict__ s_pos,
                                                  double* __restrict__ mmd_part,
                                                  float* __restrict__ out) {
    union Smem {
        struct { float Bt[2][3][2048]; } n;       // [pair][buf][8KB] = 48 KB
        struct { float ri[128], rt[128], sh2[2]; } m;
    };
    __shared__ Smem sm;
    const int t = threadIdx.x;
    const int w = t >> 6;
    const int l = t & 63;
    const int bid = blockIdx.x;

    if (bid < NEG_BLOCKS) {
        // ================= neg =================
        const int p = bid >> 8;                   // 256 blocks per p
        const int g = bid & 255;
        const int pp = w >> 1;                    // pair within block (0,1)
        const int hm = w & 1;                     // member within pair (0,1)
        const int pairid = 2 * g + pp;            // 0..511 within p
        // contiguous partition: first 106 pairs 13 tiles, rest 12 (6250 exact);
        // g<53 <=> pairid<106, so nt is block-uniform (barrier schedule needs it)
        const int nt = (g < 53) ? 13 : 12;
        const int base = (pairid < 106) ? pairid * 13 : 1378 + (pairid - 106) * 12;
        const int n16 = l & 15;
        const int q = l >> 4;

        // ---- A fragments (my bt-half) + f2 quad into registers (once) ----
        const bf16x8* Ap = Apk + (p << 11);
        bf16x8 af[4][4];                          // [kc][bt4] = 64 VGPR
        #pragma unroll
        for (int kc = 0; kc < 4; kc++)
            #pragma unroll
            for (int b4 = 0; b4 < 4; b4++)
                af[kc][b4] = Ap[kc * 512 + (hm * 4 + b4) * 64 + l];
        floatx4 f2r[4];
        #pragma unroll
        for (int b4 = 0; b4 < 4; b4++)
            f2r[b4] = *(const floatx4*)&f2w[p * 128 + (hm * 4 + b4) * 16 + q * 4];

        // ---- per-lane DMA source offsets: contiguous 1KB/instr, bit-4 pre-swizzle ----
        // LDS image L[x] = T[x ^ (((x>>9)&7)<<4)]  (involution; T = row-major tile)
        unsigned srcoff[4];
        #pragma unroll
        for (int j = 0; j < 4; j++) {
            unsigned x = (unsigned)(hm * 4096 + j * 1024 + l * 16);
            unsigned s = (x >> 9) & 7u;
            srcoff[j] = x ^ (s << 4);             // flips bit 4 only: coalescing intact
        }

        const char* tb0 = (const char*)(centers + (size_t)p * M_ * D_);
        char* myBt = (char*)&sm.n.Bt[pp][0][0];

        auto DMA = [&](int tl, int buf) {         // half-tile (4KB) per wave, 4 instrs
            const char* src = tb0 + (size_t)tl * 8192;
            char* dst = myBt + buf * 8192 + hm * 4096;
            #pragma unroll
            for (int j = 0; j < 4; j++) {
                __builtin_amdgcn_global_load_lds(
                    (const __attribute__((address_space(1))) void*)(src + srcoff[j]),
                    (__attribute__((address_space(3))) void*)(dst + j * 1024),
                    16, 0, 0);
            }
        };

        float sacc[4][4];
        #pragma unroll
        for (int b4 = 0; b4 < 4; b4++)
            #pragma unroll
            for (int r = 0; r < 4; r++) sacc[b4][r] = 0.f;

        // ---- prologue: tiles base, base+1 in flight; drain tile 0 (keeps tile 1) ----
        DMA(base, 0);
        DMA(base + 1, 1);
        asm volatile("s_waitcnt vmcnt(4)" ::: "memory");
        __builtin_amdgcn_s_barrier();

        int ib = 0;
        const unsigned sw = (unsigned)((n16 & 7) << 4);
        for (int i = 0; i < nt; i++) {
            // ---- compute tile base+i from buf ib (swizzled ds_read_b128) ----
            const char* bb = myBt + ib * 8192;
            float c2 = 0.f;
            bf16x8 bfr[4];
            #pragma unroll
            for (int kc = 0; kc < 4; kc++) {
                unsigned t0a = (unsigned)(n16 * 512 + kc * 128 + q * 32);
                union { floatx4 f; uint4 u; } h0, h1;
                h0.f = *(const floatx4*)(bb + (t0a ^ sw));
                h1.f = *(const floatx4*)(bb + ((t0a + 16) ^ sw));
                c2 += h0.f[0]*h0.f[0] + h0.f[1]*h0.f[1] + h0.f[2]*h0.f[2] + h0.f[3]*h0.f[3]
                    + h1.f[0]*h1.f[0] + h1.f[1]*h1.f[1] + h1.f[2]*h1.f[2] + h1.f[3]*h1.f[3];
                union { bf16x8 v; unsigned uu[4]; } fr;
                fr.uu[0] = pack_bf16_trunc(h0.u.x, h0.u.y);
                fr.uu[1] = pack_bf16_trunc(h0.u.z, h0.u.w);
                fr.uu[2] = pack_bf16_trunc(h1.u.x, h1.u.y);
                fr.uu[3] = pack_bf16_trunc(h1.u.z, h1.u.w);
                bfr[kc] = fr.v;
            }
            c2 += __shfl_xor(c2, 16, 64);
            c2 += __shfl_xor(c2, 32, 64);
            const float c2v = c2;

            floatx4 acc[4];
            #pragma unroll
            for (int b4 = 0; b4 < 4; b4++) acc[b4] = (floatx4)(0.f);
            #pragma unroll
            for (int kc = 0; kc < 4; kc++) {
                #pragma unroll
                for (int b4 = 0; b4 < 4; b4++)
                    acc[b4] = __builtin_amdgcn_mfma_f32_16x16x32_bf16(af[kc][b4], bfr[kc], acc[b4], 0, 0, 0);
            }

            // ---- epilogue: underflow-vote fast path ----
            float dmin = 1e30f;
            #pragma unroll
            for (int b4 = 0; b4 < 4; b4++) {
                #pragma unroll
                for (int r = 0; r < 4; r++) {
                    float d2 = fmaf(-2.f, acc[b4][r], f2r[b4][r] + c2v);
                    dmin = fminf(dmin, d2);
                }
            }
            if (__any(dmin < D2_CUT)) {
                // faithful slow path (cold): mask via direct scan
                const int gm = (base + i) * 16 + n16;   // always < M_ (exact partition)
                float vm = 1.f;
                for (int ii = 0; ii < B_ * K_; ii++) {
                    if (ci[ii] == gm) vm = 0.f;
                }
                for (int ii = 0; ii < B_; ii++) {
                    if (posi[ii] == gm) vm = 0.f;
                }
                #pragma unroll
                for (int b4 = 0; b4 < 4; b4++) {
                    #pragma unroll
                    for (int r = 0; r < 4; r++) {
                        float d2 = fmaxf(fmaf(-2.f, acc[b4][r], f2r[b4][r] + c2v), 0.f);
                        if (d2 < D2_CUT) sacc[b4][r] += vm * expf(-SCALE_ * sqrtf(d2));
                    }
                }
            }

            // ---- issue tile base+i+2 into the buffer freed by compute(i-1) ----
            if (i + 2 < nt) {
                int b2 = ib + 2; if (b2 >= 3) b2 -= 3;
                DMA(base + i + 2, b2);
                asm volatile("s_waitcnt vmcnt(4)" ::: "memory");   // drain i+1, keep i+2
            } else if (i + 1 < nt) {
                asm volatile("s_waitcnt vmcnt(0)" ::: "memory");   // drain last tile
            }
            __builtin_amdgcn_s_barrier();         // partner drained too (nt block-uniform)

            ib = (ib + 1 == 3) ? 0 : ib + 1;
        }

        // ---- per-wave reduce over m (lanes n16); guarded atomics (fast path: none) ----
        #pragma unroll
        for (int b4 = 0; b4 < 4; b4++) {
            #pragma unroll
            for (int r = 0; r < 4; r++) {
                float s = row16Sum(sacc[b4][r]);
                if (n16 == 0 && s != 0.f)
                    atomicAdd(&s_neg[p * 128 + (hm * 4 + b4) * 16 + q * 4 + r], s);
            }
        }
    } else if (bid < NEG_BLOCKS + MMD_BLOCKS) {
        // ================= mmd (row i); threads 0-127 active, coalesced stream =======
        const int i = bid - NEG_BLOCKS;
        if (t < 128) {
            sm.m.ri[t] = imgT[t * 128 + i];       // row i gather (once)
            sm.m.rt[t] = txtT[t * 128 + i];
        }
        __syncthreads();
        float kxx = 0.f, kyy = 0.f, kxy = 0.f;
        if (t < 128) {
            float dxx = 0.f, dyy = 0.f, dxy = 0.f;
            #pragma unroll 4
            for (int d = 0; d < D_; d++) {
                float rid = sm.m.ri[d], rtd = sm.m.rt[d];
                float av = imgT[d * 128 + t];     // coalesced
                float bv = txtT[d * 128 + t];
                dxx = fmaf(rid, av, dxx);
                dyy = fmaf(rtd, bv, dyy);
                dxy = fmaf(rid, bv, dxy);
            }
            kxx = (i == t) ? 0.f : expf(-fmaxf(a2i[i] + a2i[t] - 2.f * dxx, 0.f) * 0.5f);
            kyy = (i == t) ? 0.f : expf(-fmaxf(a2t[i] + a2t[t] - 2.f * dyy, 0.f) * 0.5f);
            kxy = expf(-fmaxf(a2i[i] + a2t[t] - 2.f * dxy, 0.f) * 0.5f);
        }
        float sxx = waveReduceSumOld(kxx);
        float syy = waveReduceSumOld(kyy);
        float sxy = waveReduceSumOld(kxy);
        __syncthreads();
        if (t == 0)  { sm.m.sh2[0] = sxx; }
        if (t == 64) { sm.m.sh2[1] = sxx; }
        __syncthreads();
        float txx = sm.m.sh2[0] + sm.m.sh2[1];
        __syncthreads();
        if (t == 0)  { sm.m.sh2[0] = syy; }
        if (t == 64) { sm.m.sh2[1] = syy; }
        __syncthreads();
        float tyy = sm.m.sh2[0] + sm.m.sh2[1];
        __syncthreads();
        if (t == 0)  { sm.m.sh2[0] = sxy; }
        if (t == 64) { sm.m.sh2[1] = sxy; }
        __syncthreads();
        float txy = sm.m.sh2[0] + sm.m.sh2[1];
        if (t == 0) {
            mmd_part[i] = (double)txx;
            mmd_part[128 + i] = (double)tyy;
            mmd_part[256 + i] = (double)txy;
        }
    } else {
        // ================= pos: one wave per (p,b), 4 per block ======================
        const int pair = (bid - (NEG_BLOCKS + MMD_BLOCKS)) * 4 + w;   // 0..511
        const int p = pair >> 7, b = pair & 127;
        const float* f = local + (size_t)pair * D_;
        float f0 = f[l], f1 = f[l + 64];
        float f2v = f2w[pair];
        const float* cb = centers + (size_t)p * M_ * D_;
        float s = 0.f;
        #pragma unroll
        for (int k = 0; k < K_; k++) {
            int idx = ci[b * K_ + k];
            const float* c = cb + (size_t)idx * D_;
            float c0 = c[l], c1 = c[l + 64];
            float p2 = waveSum64(c0 * c0 + c1 * c1);
            float fp = waveSum64(f0 * c0 + f1 * c1);
            float d2 = fmaxf(f2v + p2 - 2.f * fp, 0.f);
            if (d2 < D2_CUT) s += expf(-SCALE_ * sqrtf(d2));   // wave-uniform branch
        }
        if (l == 0) s_pos[pair] = s;
        if (p == 0 && l < K_) {
            int ix = ci[b * K_ + l];
            out[3 + b * K_ + l] = (float)mvid[ix];
        }
    }
}

// ---------- kernel C: final scalars ----------
__global__ __launch_bounds__(512) void k_final(const float* __restrict__ s_pos,
                                               const float* __restrict__ s_neg,
                                               const double* __restrict__ mmd_part,
                                               float* out) {
    __shared__ float red[512];
    __shared__ float lp_[4];
    int t = threadIdx.x;
    float x = logf(s_pos[t]);
    float y = logf(s_neg[t]);
    red[t] = -x + y;
    __syncthreads();
    for (int s = 64; s > 0; s >>= 1) {
        if ((t & 127) < s) red[t] += red[t + s];
        __syncthreads();
    }
    if ((t & 127) == 0) {
        float lv = red[t] / (float)B_;
        if (isnan(lv)) lv = 0.f;
        lp_[t >> 7] = lv;
    }
    __syncthreads();
    if (t == 0) {
        float local_loss = (lp_[0] + lp_[1] + lp_[2] + lp_[3]) / (float)P_;
        double sxx = 0.0, syy = 0.0, sxy = 0.0;
        for (int i = 0; i < 128; i++) {
            sxx += mmd_part[i];
            syy += mmd_part[128 + i];
            sxy += mmd_part[256 + i];
        }
        double denom = 128.0 * 127.0;
        float mmd = (float)(sxx / denom + syy / denom - 2.0 * (sxy / (128.0 * 128.0)));
        out[0] = local_loss + mmd;
        out[1] = local_loss;
        out[2] = mmd;
    }
}

extern "C" void kernel_launch(void* const* d_in, const int* in_sizes, int n_in,
                              void* d_out, int out_size, void* d_ws, size_t ws_size,
                              hipStream_t stream) {
    const float* img     = (const float*)d_in[0];
    const float* txt     = (const float*)d_in[1];
    const float* local   = (const float*)d_in[2];
    const float* centers = (const float*)d_in[3];
    const int*   ci      = (const int*)d_in[4];
    const int*   posi    = (const int*)d_in[5];
    const int*   mvid    = (const int*)d_in[6];
    float* out = (float*)d_out;

    char* ws = (char*)d_ws;
    float*  imgT     = (float*)(ws + 0);
    float*  txtT     = (float*)(ws + 65536);
    float*  a2i      = (float*)(ws + 131072);
    float*  a2t      = (float*)(ws + 131584);
    float*  f2w      = (float*)(ws + 132096);
    float*  s_pos    = (float*)(ws + 134144);
    float*  s_neg    = (float*)(ws + 136192);
    double* mmd_part = (double*)(ws + 138240);
    bf16x8* Apk      = (bf16x8*)(ws + 147456);   // 128 KB, 16B-aligned

    k_prep<<<832, 128, 0, stream>>>(img, txt, local, imgT, txtT, a2i, a2t, f2w, s_neg, Apk);
    k_negmp<<<NEG_BLOCKS + MMD_BLOCKS + POS_BLOCKS, 256, 0, stream>>>(
        centers, local, imgT, txtT, a2i, a2t, ci, posi, mvid, f2w, Apk,
        s_neg, s_pos, mmd_part, out);
    k_final<<<1, 512, 0, stream>>>(s_pos, s_neg, mmd_part, out);
}

// Round 13
// 305.556 us; speedup vs baseline: 1.1393x; 1.0039x over previous
//
#include <hip/hip_runtime.h>
#include <math.h>

#define B_ 128
#define D_ 128
#define P_ 4
#define M_ 100000
#define K_ 10
#define SCALE_ 10.0f
#define NEG_BLOCKS 2048         // 512 blocks per p; 2 wave-pairs per block; 1024 pairs per p
#define MMD_BLOCKS 128
#define POS_BLOCKS 128          // 512 (p,b) pairs / 4 waves
#define D2_CUT 120.0f           // d2 >= 120 -> exp(-10*sqrt(d2)) == 0.0f exactly (2^-158)

typedef short bf16x8 __attribute__((ext_vector_type(8)));
typedef float floatx4 __attribute__((ext_vector_type(4)));

// pack two fp32 -> two bf16 (truncate) in one v_perm_b32
__device__ inline unsigned pack_bf16_trunc(unsigned f0, unsigned f1) {
    return __builtin_amdgcn_perm(f1, f0, 0x07060302u);
}

// ---------- cross-lane helpers ----------
template <int CTRL>
__device__ inline float dpp_add(float v) {
    int x = __builtin_amdgcn_update_dpp(0, __builtin_bit_cast(int, v), CTRL, 0xF, 0xF, true);
    return v + __builtin_bit_cast(float, x);
}
__device__ inline float row16Sum(float v) {          // sum over lanes sharing l>>4
    v = dpp_add<0xB1>(v);
    v = dpp_add<0x4E>(v);
    v = dpp_add<0x141>(v);
    v = dpp_add<0x140>(v);
    return v;
}
__device__ inline float waveSum64(float v) {
    v = row16Sum(v);
    v += __shfl_xor(v, 16, 64);
    v += __shfl_xor(v, 32, 64);
    return v;
}
// legacy shfl butterfly (kept for mmd path: preserves summation order)
__device__ inline float waveReduceSumOld(float v) {
    #pragma unroll
    for (int off = 32; off > 0; off >>= 1) v += __shfl_xor(v, off, 64);
    return v;
}
__device__ inline float blockReduce128(float v, float* sh2) {  // 128-thread blocks
    v = waveSum64(v);
    int wid = threadIdx.x >> 6;
    if ((threadIdx.x & 63) == 0) sh2[wid] = v;
    __syncthreads();
    float r = sh2[0] + sh2[1];
    __syncthreads();
    return r;
}

// ---------- kernel A: normalize (transposed out) + f2 + zero s_neg + A-pack ----------
__global__ __launch_bounds__(128) void k_prep(const float* __restrict__ img,
                                              const float* __restrict__ txt,
                                              const float* __restrict__ local,
                                              float* imgT, float* txtT,
                                              float* a2i, float* a2t,
                                              float* f2w, float* s_neg,
                                              bf16x8* __restrict__ Apk) {
    __shared__ float sh2[2];
    int bid = blockIdx.x, t = threadIdx.x;
    if (bid < 256) {
        int row = bid & 127, which = bid >> 7;
        if (bid < 4) s_neg[bid * 128 + t] = 0.f;
        const float* src = which ? txt : img;
        float* dstT = which ? txtT : imgT;
        float* a2 = which ? a2t : a2i;
        float v = src[row * D_ + t];
        float s = blockReduce128(v * v, sh2);
        float n = v / sqrtf(s);
        dstT[t * 128 + row] = n;                  // transposed for coalesced mmd stream
        float s2 = blockReduce128(n * n, sh2);
        if (t == 0) a2[row] = s2;
    } else if (bid < 768) {
        int r = bid - 256;                        // 0..511 = (p,b)
        float v = local[(size_t)r * D_ + t];
        float s = blockReduce128(v * v, sh2);
        if (t == 0) f2w[r] = s;
    } else {
        // pack A = local[p] into bf16 MFMA fragments ONCE
        int g = (bid - 768) * 128 + t;            // 0..8191 global fragment id
        int p = g >> 11, f = g & 2047;
        int fl = f & 63, bt = (f >> 6) & 7, kc = f >> 9;
        int row = bt * 16 + (fl & 15);
        int col = kc * 32 + ((fl >> 4) & 3) * 8;
        const float* lp = local + (size_t)p * B_ * D_ + row * D_ + col;
        const uint4 u0 = *(const uint4*)lp;
        const uint4 u1 = *(const uint4*)(lp + 4);
        union { bf16x8 v; unsigned u[4]; } fr;
        fr.u[0] = pack_bf16_trunc(u0.x, u0.y);
        fr.u[1] = pack_bf16_trunc(u0.z, u0.w);
        fr.u[2] = pack_bf16_trunc(u1.x, u1.y);
        fr.u[3] = pack_bf16_trunc(u1.z, u1.w);
        Apk[g] = fr.v;                            // coalesced 16B store, fragment-linear
    }
}

// ---------- kernel B: neg (R12 structure, 2x blocks again) + mmd + pos ----------
// R12 (1024 blocks) = 306.8us best: grid 512->1024 filled the 3rd residency slot
// (LDS 48KB + VGPR ~132 cap at 3 blocks/CU) -> 6 pair-streams/CU, -12us.
// Single change here: NEG_BLOCKS 1024 -> 2048 (nt=6/7). Residency stays 3; the
// lever is backfill granularity — 8 short blocks per CU keep all 3 slots full
// deeper into the tail and overlap incoming-block prologues with outgoing drains.
// Partition exact: 6250 = 106*7 + 918*6, boundary at pairid 106 (g<53) keeps nt
// block-uniform for the paired-barrier schedule.
__global__ __launch_bounds__(256, 2) void k_negmp(const float* __restrict__ centers,
                                                  const float* __restrict__ local,
                                                  const float* __restrict__ imgT,
                                                  const float* __restrict__ txtT,
                                                  const float* __restrict__ a2i,
                                                  const float* __restrict__ a2t,
                                                  const int* __restrict__ ci,
                                                  const int* __restrict__ posi,
                                                  const int* __restrict__ mvid,
                                                  const float* __restrict__ f2w,
                                                  const bf16x8* __restrict__ Apk,
                                                  float* __restrict__ s_neg,
                                                  float* __restrict__ s_pos,
                                                  double* __restrict__ mmd_part,
                                                  float* __restrict__ out) {
    union Smem {
        struct { float Bt[2][3][2048]; } n;       // [pair][buf][8KB] = 48 KB
        struct { float ri[128], rt[128], sh2[2]; } m;
    };
    __shared__ Smem sm;
    const int t = threadIdx.x;
    const int w = t >> 6;
    const int l = t & 63;
    const int bid = blockIdx.x;

    if (bid < NEG_BLOCKS) {
        // ================= neg =================
        const int p = bid >> 9;                   // 512 blocks per p
        const int g = bid & 511;
        const int pp = w >> 1;                    // pair within block (0,1)
        const int hm = w & 1;                     // member within pair (0,1)
        const int pairid = 2 * g + pp;            // 0..1023 within p
        // contiguous partition: first 106 pairs 7 tiles, rest 6 (6250 exact);
        // g<53 <=> pairid<106, so nt is block-uniform (barrier schedule needs it)
        const int nt = (g < 53) ? 7 : 6;
        const int base = (pairid < 106) ? pairid * 7 : 742 + (pairid - 106) * 6;
        const int n16 = l & 15;
        const int q = l >> 4;

        // ---- A fragments (my bt-half) + f2 quad into registers (once) ----
        const bf16x8* Ap = Apk + (p << 11);
        bf16x8 af[4][4];                          // [kc][bt4] = 64 VGPR
        #pragma unroll
        for (int kc = 0; kc < 4; kc++)
            #pragma unroll
            for (int b4 = 0; b4 < 4; b4++)
                af[kc][b4] = Ap[kc * 512 + (hm * 4 + b4) * 64 + l];
        floatx4 f2r[4];
        #pragma unroll
        for (int b4 = 0; b4 < 4; b4++)
            f2r[b4] = *(const floatx4*)&f2w[p * 128 + (hm * 4 + b4) * 16 + q * 4];

        // ---- per-lane DMA source offsets: contiguous 1KB/instr, bit-4 pre-swizzle ----
        // LDS image L[x] = T[x ^ (((x>>9)&7)<<4)]  (involution; T = row-major tile)
        unsigned srcoff[4];
        #pragma unroll
        for (int j = 0; j < 4; j++) {
            unsigned x = (unsigned)(hm * 4096 + j * 1024 + l * 16);
            unsigned s = (x >> 9) & 7u;
            srcoff[j] = x ^ (s << 4);             // flips bit 4 only: coalescing intact
        }

        const char* tb0 = (const char*)(centers + (size_t)p * M_ * D_);
        char* myBt = (char*)&sm.n.Bt[pp][0][0];

        auto DMA = [&](int tl, int buf) {         // half-tile (4KB) per wave, 4 instrs
            const char* src = tb0 + (size_t)tl * 8192;
            char* dst = myBt + buf * 8192 + hm * 4096;
            #pragma unroll
            for (int j = 0; j < 4; j++) {
                __builtin_amdgcn_global_load_lds(
                    (const __attribute__((address_space(1))) void*)(src + srcoff[j]),
                    (__attribute__((address_space(3))) void*)(dst + j * 1024),
                    16, 0, 0);
            }
        };

        float sacc[4][4];
        #pragma unroll
        for (int b4 = 0; b4 < 4; b4++)
            #pragma unroll
            for (int r = 0; r < 4; r++) sacc[b4][r] = 0.f;

        // ---- prologue: tiles base, base+1 in flight; drain tile 0 (keeps tile 1) ----
        DMA(base, 0);
        DMA(base + 1, 1);
        asm volatile("s_waitcnt vmcnt(4)" ::: "memory");
        __builtin_amdgcn_s_barrier();

        int ib = 0;
        const unsigned sw = (unsigned)((n16 & 7) << 4);
        for (int i = 0; i < nt; i++) {
            // ---- compute tile base+i from buf ib (swizzled ds_read_b128) ----
            const char* bb = myBt + ib * 8192;
            float c2 = 0.f;
            bf16x8 bfr[4];
            #pragma unroll
            for (int kc = 0; kc < 4; kc++) {
                unsigned t0a = (unsigned)(n16 * 512 + kc * 128 + q * 32);
                union { floatx4 f; uint4 u; } h0, h1;
                h0.f = *(const floatx4*)(bb + (t0a ^ sw));
                h1.f = *(const floatx4*)(bb + ((t0a + 16) ^ sw));
                c2 += h0.f[0]*h0.f[0] + h0.f[1]*h0.f[1] + h0.f[2]*h0.f[2] + h0.f[3]*h0.f[3]
                    + h1.f[0]*h1.f[0] + h1.f[1]*h1.f[1] + h1.f[2]*h1.f[2] + h1.f[3]*h1.f[3];
                union { bf16x8 v; unsigned uu[4]; } fr;
                fr.uu[0] = pack_bf16_trunc(h0.u.x, h0.u.y);
                fr.uu[1] = pack_bf16_trunc(h0.u.z, h0.u.w);
                fr.uu[2] = pack_bf16_trunc(h1.u.x, h1.u.y);
                fr.uu[3] = pack_bf16_trunc(h1.u.z, h1.u.w);
                bfr[kc] = fr.v;
            }
            c2 += __shfl_xor(c2, 16, 64);
            c2 += __shfl_xor(c2, 32, 64);
            const float c2v = c2;

            floatx4 acc[4];
            #pragma unroll
            for (int b4 = 0; b4 < 4; b4++) acc[b4] = (floatx4)(0.f);
            #pragma unroll
            for (int kc = 0; kc < 4; kc++) {
                #pragma unroll
                for (int b4 = 0; b4 < 4; b4++)
                    acc[b4] = __builtin_amdgcn_mfma_f32_16x16x32_bf16(af[kc][b4], bfr[kc], acc[b4], 0, 0, 0);
            }

            // ---- epilogue: underflow-vote fast path ----
            float dmin = 1e30f;
            #pragma unroll
            for (int b4 = 0; b4 < 4; b4++) {
                #pragma unroll
                for (int r = 0; r < 4; r++) {
                    float d2 = fmaf(-2.f, acc[b4][r], f2r[b4][r] + c2v);
                    dmin = fminf(dmin, d2);
                }
            }
            if (__any(dmin < D2_CUT)) {
                // faithful slow path (cold): mask via direct scan
                const int gm = (base + i) * 16 + n16;   // always < M_ (exact partition)
                float vm = 1.f;
                for (int ii = 0; ii < B_ * K_; ii++) {
                    if (ci[ii] == gm) vm = 0.f;
                }
                for (int ii = 0; ii < B_; ii++) {
                    if (posi[ii] == gm) vm = 0.f;
                }
                #pragma unroll
                for (int b4 = 0; b4 < 4; b4++) {
                    #pragma unroll
                    for (int r = 0; r < 4; r++) {
                        float d2 = fmaxf(fmaf(-2.f, acc[b4][r], f2r[b4][r] + c2v), 0.f);
                        if (d2 < D2_CUT) sacc[b4][r] += vm * expf(-SCALE_ * sqrtf(d2));
                    }
                }
            }

            // ---- issue tile base+i+2 into the buffer freed by compute(i-1) ----
            if (i + 2 < nt) {
                int b2 = ib + 2; if (b2 >= 3) b2 -= 3;
                DMA(base + i + 2, b2);
                asm volatile("s_waitcnt vmcnt(4)" ::: "memory");   // drain i+1, keep i+2
            } else if (i + 1 < nt) {
                asm volatile("s_waitcnt vmcnt(0)" ::: "memory");   // drain last tile
            }
            __builtin_amdgcn_s_barrier();         // partner drained too (nt block-uniform)

            ib = (ib + 1 == 3) ? 0 : ib + 1;
        }

        // ---- per-wave reduce over m (lanes n16); guarded atomics (fast path: none) ----
        #pragma unroll
        for (int b4 = 0; b4 < 4; b4++) {
            #pragma unroll
            for (int r = 0; r < 4; r++) {
                float s = row16Sum(sacc[b4][r]);
                if (n16 == 0 && s != 0.f)
                    atomicAdd(&s_neg[p * 128 + (hm * 4 + b4) * 16 + q * 4 + r], s);
            }
        }
    } else if (bid < NEG_BLOCKS + MMD_BLOCKS) {
        // ================= mmd (row i); threads 0-127 active, coalesced stream =======
        const int i = bid - NEG_BLOCKS;
        if (t < 128) {
            sm.m.ri[t] = imgT[t * 128 + i];       // row i gather (once)
            sm.m.rt[t] = txtT[t * 128 + i];
        }
        __syncthreads();
        float kxx = 0.f, kyy = 0.f, kxy = 0.f;
        if (t < 128) {
            float dxx = 0.f, dyy = 0.f, dxy = 0.f;
            #pragma unroll 4
            for (int d = 0; d < D_; d++) {
                float rid = sm.m.ri[d], rtd = sm.m.rt[d];
                float av = imgT[d * 128 + t];     // coalesced
                float bv = txtT[d * 128 + t];
                dxx = fmaf(rid, av, dxx);
                dyy = fmaf(rtd, bv, dyy);
                dxy = fmaf(rid, bv, dxy);
            }
            kxx = (i == t) ? 0.f : expf(-fmaxf(a2i[i] + a2i[t] - 2.f * dxx, 0.f) * 0.5f);
            kyy = (i == t) ? 0.f : expf(-fmaxf(a2t[i] + a2t[t] - 2.f * dyy, 0.f) * 0.5f);
            kxy = expf(-fmaxf(a2i[i] + a2t[t] - 2.f * dxy, 0.f) * 0.5f);
        }
        float sxx = waveReduceSumOld(kxx);
        float syy = waveReduceSumOld(kyy);
        float sxy = waveReduceSumOld(kxy);
        __syncthreads();
        if (t == 0)  { sm.m.sh2[0] = sxx; }
        if (t == 64) { sm.m.sh2[1] = sxx; }
        __syncthreads();
        float txx = sm.m.sh2[0] + sm.m.sh2[1];
        __syncthreads();
        if (t == 0)  { sm.m.sh2[0] = syy; }
        if (t == 64) { sm.m.sh2[1] = syy; }
        __syncthreads();
        float tyy = sm.m.sh2[0] + sm.m.sh2[1];
        __syncthreads();
        if (t == 0)  { sm.m.sh2[0] = sxy; }
        if (t == 64) { sm.m.sh2[1] = sxy; }
        __syncthreads();
        float txy = sm.m.sh2[0] + sm.m.sh2[1];
        if (t == 0) {
            mmd_part[i] = (double)txx;
            mmd_part[128 + i] = (double)tyy;
            mmd_part[256 + i] = (double)txy;
        }
    } else {
        // ================= pos: one wave per (p,b), 4 per block ======================
        const int pair = (bid - (NEG_BLOCKS + MMD_BLOCKS)) * 4 + w;   // 0..511
        const int p = pair >> 7, b = pair & 127;
        const float* f = local + (size_t)pair * D_;
        float f0 = f[l], f1 = f[l + 64];
        float f2v = f2w[pair];
        const float* cb = centers + (size_t)p * M_ * D_;
        float s = 0.f;
        #pragma unroll
        for (int k = 0; k < K_; k++) {
            int idx = ci[b * K_ + k];
            const float* c = cb + (size_t)idx * D_;
            float c0 = c[l], c1 = c[l + 64];
            float p2 = waveSum64(c0 * c0 + c1 * c1);
            float fp = waveSum64(f0 * c0 + f1 * c1);
            float d2 = fmaxf(f2v + p2 - 2.f * fp, 0.f);
            if (d2 < D2_CUT) s += expf(-SCALE_ * sqrtf(d2));   // wave-uniform branch
        }
        if (l == 0) s_pos[pair] = s;
        if (p == 0 && l < K_) {
            int ix = ci[b * K_ + l];
            out[3 + b * K_ + l] = (float)mvid[ix];
        }
    }
}

// ---------- kernel C: final scalars ----------
__global__ __launch_bounds__(512) void k_final(const float* __restrict__ s_pos,
                                               const float* __restrict__ s_neg,
                                               const double* __restrict__ mmd_part,
                                               float* out) {
    __shared__ float red[512];
    __shared__ float lp_[4];
    int t = threadIdx.x;
    float x = logf(s_pos[t]);
    float y = logf(s_neg[t]);
    red[t] = -x + y;
    __syncthreads();
    for (int s = 64; s > 0; s >>= 1) {
        if ((t & 127) < s) red[t] += red[t + s];
        __syncthreads();
    }
    if ((t & 127) == 0) {
        float lv = red[t] / (float)B_;
        if (isnan(lv)) lv = 0.f;
        lp_[t >> 7] = lv;
    }
    __syncthreads();
    if (t == 0) {
        float local_loss = (lp_[0] + lp_[1] + lp_[2] + lp_[3]) / (float)P_;
        double sxx = 0.0, syy = 0.0, sxy = 0.0;
        for (int i = 0; i < 128; i++) {
            sxx += mmd_part[i];
            syy += mmd_part[128 + i];
            sxy += mmd_part[256 + i];
        }
        double denom = 128.0 * 127.0;
        float mmd = (float)(sxx / denom + syy / denom - 2.0 * (sxy / (128.0 * 128.0)));
        out[0] = local_loss + mmd;
        out[1] = local_loss;
        out[2] = mmd;
    }
}

extern "C" void kernel_launch(void* const* d_in, const int* in_sizes, int n_in,
                              void* d_out, int out_size, void* d_ws, size_t ws_size,
                              hipStream_t stream) {
    const float* img     = (const float*)d_in[0];
    const float* txt     = (const float*)d_in[1];
    const float* local   = (const float*)d_in[2];
    const float* centers = (const float*)d_in[3];
    const int*   ci      = (const int*)d_in[4];
    const int*   posi    = (const int*)d_in[5];
    const int*   mvid    = (const int*)d_in[6];
    float* out = (float*)d_out;

    char* ws = (char*)d_ws;
    float*  imgT     = (float*)(ws + 0);
    float*  txtT     = (float*)(ws + 65536);
    float*  a2i      = (float*)(ws + 131072);
    float*  a2t      = (float*)(ws + 131584);
    float*  f2w      = (float*)(ws + 132096);
    float*  s_pos    = (float*)(ws + 134144);
    float*  s_neg    = (float*)(ws + 136192);
    double* mmd_part = (double*)(ws + 138240);
    bf16x8* Apk      = (bf16x8*)(ws + 147456);   // 128 KB, 16B-aligned

    k_prep<<<832, 128, 0, stream>>>(img, txt, local, imgT, txtT, a2i, a2t, f2w, s_neg, Apk);
    k_negmp<<<NEG_BLOCKS + MMD_BLOCKS + POS_BLOCKS, 256, 0, stream>>>(
        centers, local, imgT, txtT, a2i, a2t, ci, posi, mvid, f2w, Apk,
        s_neg, s_pos, mmd_part, out);
    k_final<<<1, 512, 0, stream>>>(s_pos, s_neg, mmd_part, out);
}